// Round 1
// baseline (1052.122 us; speedup 1.0000x reference)
//
#include <hip/hip_runtime.h>

typedef unsigned short u16;
typedef unsigned int u32;

#define EN_CAP 192

__device__ __forceinline__ float bf2f(u16 h) { return __uint_as_float(((u32)h) << 16); }
__device__ __forceinline__ float bflo(u32 u) { return __uint_as_float(u << 16); }
__device__ __forceinline__ float bfhi(u32 u) { return __uint_as_float(u & 0xffff0000u); }
__device__ __forceinline__ u16 f2bf(float f) {
    u32 x = __float_as_uint(f);
    u32 r = (x + 0x7fffu + ((x >> 16) & 1u)) >> 16;  // RNE
    return (u16)r;
}

// ---------------- K0a: A_h = W_node @ Wk_r[h], B_h = W_node @ Wk_s[h] ----------------
__global__ void k0a_kernel(const float* __restrict__ Wn, const float* __restrict__ Wks,
                           const float* __restrict__ Wkr, float* __restrict__ A,
                           float* __restrict__ B) {
    int idx = blockIdx.x * 256 + threadIdx.x;  // 2*4*64*128 = 65536
    if (idx >= 65536) return;
    int which = idx >> 15;
    int rem = idx & 32767;
    int h = rem >> 13;
    int r = rem & 8191;
    int a = r >> 7, dp = r & 127;
    const float* W = which ? Wks : Wkr;
    float acc = 0.f;
    for (int d = 0; d < 128; ++d)
        acc += Wn[a * 128 + d] * W[(h * 128 + d) * 128 + dp];
    (which ? B : A)[(h * 64 + a) * 128 + dp] = acc;
}

// ---------------- K0a2: ybr_h = b_node@Wk_r[h] + bk_r[h]; ybs_h likewise with s ------
__global__ void k0a2_kernel(const float* __restrict__ bn, const float* __restrict__ Wks,
                            const float* __restrict__ Wkr, const float* __restrict__ bks,
                            const float* __restrict__ bkr, float* __restrict__ ybs,
                            float* __restrict__ ybr) {
    int idx = blockIdx.x * 256 + threadIdx.x;  // 2*4*128 = 1024
    if (idx >= 1024) return;
    int which = idx >> 9;
    int rem = idx & 511;
    int h = rem >> 7, dp = rem & 127;
    const float* W = which ? Wks : Wkr;
    const float* b = which ? bks : bkr;
    float acc = b[h * 128 + dp];
    for (int d = 0; d < 128; ++d) acc += bn[d] * W[(h * 128 + d) * 128 + dp];
    (which ? ybs : ybr)[h * 128 + dp] = acc;
}

// ---------------- K0b: assemble Wfold [64 x 712] + biasrow[712] ----------------------
// cols: [0:128) x | [128:640) v(h,i) | [640:704) u(h,k) | [704:708) d0_h | [708:712) c0_h
__global__ void k0b_kernel(const float* __restrict__ Wn, const float* __restrict__ bn,
                           const float* __restrict__ A, const float* __restrict__ B,
                           const float* __restrict__ ybr, const float* __restrict__ ybs,
                           const float* __restrict__ Wks, const float* __restrict__ Wedge,
                           const float* __restrict__ bks, const float* __restrict__ bedge,
                           float* __restrict__ Wfold, float* __restrict__ biasrow) {
    int idx = blockIdx.x * 256 + threadIdx.x;  // 65*712
    if (idx >= 65 * 712) return;
    int a = idx / 712, c = idx % 712;
    float val;
    if (c < 128) {
        val = (a < 64) ? Wn[a * 128 + c] : bn[c];
    } else if (c < 640) {
        int h = (c - 128) >> 7, i = (c - 128) & 127;
        const float* rv = (a < 64) ? &A[(h * 64 + a) * 128] : &ybr[h * 128];
        float s = 0.f;
        for (int d = 0; d < 128; ++d) s += rv[d] * Wks[(h * 128 + i) * 128 + d];
        val = s;
    } else if (c < 704) {
        int h = (c - 640) >> 4, k = (c - 640) & 15;
        const float* rv = (a < 64) ? &B[(h * 64 + a) * 128] : &ybs[h * 128];
        float s = 0.f;
        for (int d = 0; d < 128; ++d) s += rv[d] * Wedge[k * 128 + d];
        val = s;
    } else if (c < 708) {
        int h = c - 704;
        const float* rv = (a < 64) ? &A[(h * 64 + a) * 128] : &ybr[h * 128];
        float s = 0.f;
        for (int d = 0; d < 128; ++d) s += rv[d] * bks[h * 128 + d];
        val = s;
    } else {
        int h = c - 708;
        const float* rv = (a < 64) ? &B[(h * 64 + a) * 128] : &ybs[h * 128];
        float s = 0.f;
        for (int d = 0; d < 128; ++d) s += rv[d] * bedge[d];
        val = s;
    }
    if (a < 64) Wfold[(size_t)a * 712 + c] = val;
    else biasrow[c] = val;
}

// ---------------- G1: T[N,704](bf16), S[N,8](f32) = nodes[N,64] @ Wfold + bias -------
__global__ __launch_bounds__(256) void g1_kernel(const float* __restrict__ nodes,
                                                 const float* __restrict__ Wfold,
                                                 const float* __restrict__ biasrow,
                                                 u16* __restrict__ T, float* __restrict__ S,
                                                 int N) {
    __shared__ float Al[64][65];
    __shared__ float Wl[64][65];
    int t = threadIdx.x;
    int r0 = blockIdx.x * 64, c0 = blockIdx.y * 64;
    for (int i = t; i < 4096; i += 256) {
        int r = i >> 6, k = i & 63;
        Al[r][k] = (r0 + r < N) ? nodes[(size_t)(r0 + r) * 64 + k] : 0.f;
        Wl[r][k] = (c0 + k < 712) ? Wfold[(size_t)r * 712 + c0 + k] : 0.f;
    }
    __syncthreads();
    int cg = t & 15, ng = t >> 4;
    float acc[4][4] = {};
    for (int k = 0; k < 64; ++k) {
        float a_[4], w_[4];
#pragma unroll
        for (int i = 0; i < 4; ++i) a_[i] = Al[ng + 16 * i][k];
#pragma unroll
        for (int j = 0; j < 4; ++j) w_[j] = Wl[k][cg + 16 * j];
#pragma unroll
        for (int i = 0; i < 4; ++i)
#pragma unroll
            for (int j = 0; j < 4; ++j) acc[i][j] += a_[i] * w_[j];
    }
#pragma unroll
    for (int i = 0; i < 4; ++i) {
#pragma unroll
        for (int j = 0; j < 4; ++j) {
            int r = r0 + ng + 16 * i, c = c0 + cg + 16 * j;
            if (r < N && c < 712) {
                float val = acc[i][j] + biasrow[c];
                if (c < 704) T[(size_t)r * 704 + c] = f2bf(val);
                else if (c < 708) S[(size_t)r * 8 + (c - 704)] = val;
                else S[(size_t)r * 8 + 4 + (c - 708)] = val;
            }
        }
    }
}

// ---------------- CSR build ----------------------------------------------------------
__global__ void hist_kernel(const int* __restrict__ recv, int* __restrict__ deg, int E) {
    int e = blockIdx.x * 256 + threadIdx.x;
    if (e < E) atomicAdd(&deg[recv[e]], 1);
}

__global__ __launch_bounds__(1024) void scan_kernel(const int* __restrict__ deg,
                                                    int* __restrict__ row_start,
                                                    int* __restrict__ cursor, int N) {
    __shared__ int sm[1024];
    int t = threadIdx.x;
    int C = (N + 1023) >> 10;
    int base = t * C;
    int s = 0;
    for (int i = 0; i < C; ++i) {
        int idx = base + i;
        if (idx < N) s += deg[idx];
    }
    sm[t] = s;
    __syncthreads();
    for (int off = 1; off < 1024; off <<= 1) {
        int v = (t >= off) ? sm[t - off] : 0;
        __syncthreads();
        sm[t] += v;
        __syncthreads();
    }
    int run = (t == 0) ? 0 : sm[t - 1];
    for (int i = 0; i < C; ++i) {
        int idx = base + i;
        if (idx < N) {
            row_start[idx] = run;
            cursor[idx] = run;
            run += deg[idx];
        }
    }
    if (t == 1023) row_start[N] = sm[1023];
}

__global__ void scatter_kernel(const int* __restrict__ recv, int* __restrict__ cursor,
                               int* __restrict__ eidx, int E) {
    int e = blockIdx.x * 256 + threadIdx.x;
    if (e < E) {
        int p = atomicAdd(&cursor[recv[e]], 1);
        eidx[p] = e;
    }
}

// ---------------- EN: per-receiver-node softmax attention + aggregation --------------
__device__ __forceinline__ float en_logit_g(const u16* __restrict__ T,
                                            const float* __restrict__ S,
                                            const float* __restrict__ edges, int e, int s,
                                            int g, int k16, uint4 vv, float d0g) {
    const u16* Ts = T + (size_t)s * 704;
    uint4 xs = *(const uint4*)(Ts + 8 * k16);
    float ev = edges[(size_t)e * 16 + k16];
    float uu = bf2f(Ts[640 + g * 16 + k16]);
    float part = ev * uu;
    part += bflo(xs.x) * bflo(vv.x) + bfhi(xs.x) * bfhi(vv.x);
    part += bflo(xs.y) * bflo(vv.y) + bfhi(xs.y) * bfhi(vv.y);
    part += bflo(xs.z) * bflo(vv.z) + bfhi(xs.z) * bfhi(vv.z);
    part += bflo(xs.w) * bflo(vv.w) + bfhi(xs.w) * bfhi(vv.w);
#pragma unroll
    for (int o = 8; o > 0; o >>= 1) part += __shfl_xor(part, o);
    return 0.08838834764831843f * (part + d0g + S[(size_t)s * 8 + 4 + g]);
}

__global__ __launch_bounds__(256) void en_kernel(const int* __restrict__ row_start,
                                                 const int* __restrict__ eidx,
                                                 const int* __restrict__ senders,
                                                 const float* __restrict__ edges,
                                                 const u16* __restrict__ T,
                                                 const float* __restrict__ S,
                                                 const float* __restrict__ W_edge,
                                                 const float* __restrict__ b_edge,
                                                 u16* __restrict__ agg, int N) {
    __shared__ float plds[4][EN_CAP * 4];
    int t = threadIdx.x;
    int wid = t >> 6, lane = t & 63;
    int g = lane >> 4, k16 = lane & 15;
    int n = blockIdx.x * 4 + wid;
    if (n >= N) return;
    int rs = row_start[n];
    int deg = row_start[n + 1] - rs;
    float* pl = plds[wid];
    const u16* Trow = T + (size_t)n * 704;
    uint4 vv = *(const uint4*)(Trow + 128 + g * 128 + 8 * k16);
    float d0g = S[(size_t)n * 8 + g];
    float2 wreg[16];
#pragma unroll
    for (int k = 0; k < 16; ++k) wreg[k] = *(const float2*)&W_edge[k * 128 + 2 * lane];
    float be0 = b_edge[2 * lane], be1 = b_edge[2 * lane + 1];

    bool fits = (deg <= EN_CAP);
    float mh_g = -1e30f;
    for (int j = 0; j < deg; ++j) {
        int e = __builtin_amdgcn_readfirstlane(eidx[rs + j]);
        int s = __builtin_amdgcn_readfirstlane(senders[e]);
        float lgg = en_logit_g(T, S, edges, e, s, g, k16, vv, d0g);
        mh_g = fmaxf(mh_g, lgg);
        if (fits && k16 == 0) pl[j * 4 + g] = lgg;
    }
    float mhall[4], ssum[4] = {0.f, 0.f, 0.f, 0.f};
#pragma unroll
    for (int h = 0; h < 4; ++h) mhall[h] = __shfl(mh_g, h * 16);

    if (fits) {
        for (int j = lane; j < deg; j += 64) {
#pragma unroll
            for (int h = 0; h < 4; ++h) {
                float p = __expf(pl[j * 4 + h] - mhall[h]);
                pl[j * 4 + h] = p;
                ssum[h] += p;
            }
        }
#pragma unroll
        for (int h = 0; h < 4; ++h) {
#pragma unroll
            for (int o = 32; o > 0; o >>= 1) ssum[h] += __shfl_xor(ssum[h], o);
        }
    } else {
        float sg = 0.f;
        for (int j = 0; j < deg; ++j) {
            int e = __builtin_amdgcn_readfirstlane(eidx[rs + j]);
            int s = __builtin_amdgcn_readfirstlane(senders[e]);
            float lgg = en_logit_g(T, S, edges, e, s, g, k16, vv, d0g);
            sg += __expf(lgg - mh_g);
        }
#pragma unroll
        for (int h = 0; h < 4; ++h) ssum[h] = __shfl(sg, h * 16);
    }

    float a0[4] = {0.f, 0.f, 0.f, 0.f}, a1[4] = {0.f, 0.f, 0.f, 0.f};
    for (int j = 0; j < deg; ++j) {
        int e = __builtin_amdgcn_readfirstlane(eidx[rs + j]);
        int s = __builtin_amdgcn_readfirstlane(senders[e]);
        float p[4];
        if (fits) {
            p[0] = pl[j * 4 + 0];
            p[1] = pl[j * 4 + 1];
            p[2] = pl[j * 4 + 2];
            p[3] = pl[j * 4 + 3];
        } else {
            float lgg = en_logit_g(T, S, edges, e, s, g, k16, vv, d0g);
#pragma unroll
            for (int h = 0; h < 4; ++h) p[h] = __expf(__shfl(lgg, h * 16) - mhall[h]);
        }
        const u16* Ts = T + (size_t)s * 704;
        u32 xs = *(const u32*)(Ts + 2 * lane);
        float m0 = bflo(xs) + be0;
        float m1 = bfhi(xs) + be1;
#pragma unroll
        for (int k = 0; k < 16; ++k) {
            float evk = edges[(size_t)e * 16 + k];
            m0 += evk * wreg[k].x;
            m1 += evk * wreg[k].y;
        }
#pragma unroll
        for (int h = 0; h < 4; ++h) {
            a0[h] += p[h] * m0;
            a1[h] += p[h] * m1;
        }
    }
#pragma unroll
    for (int h = 0; h < 4; ++h) {
        float inv = (ssum[h] > 0.f) ? 1.f / ssum[h] : 0.f;
        u32 lo = f2bf(a0[h] * inv), hi = f2bf(a1[h] * inv);
        *(u32*)(agg + (size_t)n * 512 + h * 128 + 2 * lane) = (hi << 16) | lo;
    }
}

// ---------------- G3: out = relu(x + agg @ W_out + b_out)  (or head-mean path) -------
__global__ __launch_bounds__(256) void g3_kernel(const u16* __restrict__ T,
                                                 const u16* __restrict__ agg,
                                                 const float* __restrict__ Wout,
                                                 const float* __restrict__ bout,
                                                 const int* __restrict__ avgflag,
                                                 float* __restrict__ out, int N) {
    int t = threadIdx.x;
    int r0 = blockIdx.x * 32;
    if (*avgflag) {
        for (int i = t; i < 32 * 128; i += 256) {
            int n = r0 + (i >> 7), j = i & 127;
            if (n < N) {
                float s = 0.f;
#pragma unroll
                for (int h = 0; h < 4; ++h) s += bf2f(agg[(size_t)n * 512 + h * 128 + j]);
                float v = bf2f(T[(size_t)n * 704 + j]) + 0.25f * s;
                out[(size_t)n * 128 + j] = v > 0.f ? v : 0.f;
            }
        }
        return;
    }
    __shared__ float Wl[64][129];
    __shared__ float Al[32][65];
    int cg = t & 31, ng = t >> 5;
    float acc[4][4] = {};
    for (int k0 = 0; k0 < 512; k0 += 64) {
        __syncthreads();
        for (int i = t; i < 8192; i += 256) {
            int kk = i >> 7, c = i & 127;
            Wl[kk][c] = Wout[(size_t)(k0 + kk) * 128 + c];
        }
        for (int i = t; i < 2048; i += 256) {
            int nn = i >> 6, kk = i & 63;
            Al[nn][kk] = (r0 + nn < N) ? bf2f(agg[(size_t)(r0 + nn) * 512 + k0 + kk]) : 0.f;
        }
        __syncthreads();
        for (int k = 0; k < 64; ++k) {
            float a_[4], w_[4];
#pragma unroll
            for (int i = 0; i < 4; ++i) a_[i] = Al[ng + 8 * i][k];
#pragma unroll
            for (int j = 0; j < 4; ++j) w_[j] = Wl[k][cg + 32 * j];
#pragma unroll
            for (int i = 0; i < 4; ++i)
#pragma unroll
                for (int j = 0; j < 4; ++j) acc[i][j] += a_[i] * w_[j];
        }
    }
#pragma unroll
    for (int i = 0; i < 4; ++i) {
#pragma unroll
        for (int j = 0; j < 4; ++j) {
            int n = r0 + ng + 8 * i, c = cg + 32 * j;
            if (n < N) {
                float v = acc[i][j] + bout[c] + bf2f(T[(size_t)n * 704 + c]);
                out[(size_t)n * 128 + c] = v > 0.f ? v : 0.f;
            }
        }
    }
}

// ---------------- launch --------------------------------------------------------------
extern "C" void kernel_launch(void* const* d_in, const int* in_sizes, int n_in, void* d_out,
                              int out_size, void* d_ws, size_t ws_size, hipStream_t stream) {
    const float* nodes = (const float*)d_in[0];
    const float* edges = (const float*)d_in[1];
    const int* senders = (const int*)d_in[2];
    const int* receivers = (const int*)d_in[3];
    const int* avgflag = (const int*)d_in[4];
    const float* W_node = (const float*)d_in[5];
    const float* b_node = (const float*)d_in[6];
    const float* W_edge = (const float*)d_in[7];
    const float* b_edge = (const float*)d_in[8];
    const float* Wk_s = (const float*)d_in[9];
    const float* bk_s = (const float*)d_in[10];
    const float* Wk_r = (const float*)d_in[11];
    const float* bk_r = (const float*)d_in[12];
    const float* W_out = (const float*)d_in[13];
    const float* b_out = (const float*)d_in[14];
    int N = in_sizes[0] / 64;
    int E = in_sizes[2];
    float* outp = (float*)d_out;

    char* base = (char*)d_ws;
    size_t off = 0;
    auto alloc = [&](size_t nbytes) -> char* {
        char* p = base + off;
        off = (off + nbytes + 255) & ~(size_t)255;
        return p;
    };
    u16* T = (u16*)alloc((size_t)N * 704 * 2);
    float* S = (float*)alloc((size_t)N * 8 * 4);
    u16* agg = (u16*)alloc((size_t)N * 512 * 2);
    int* deg = (int*)alloc((size_t)N * 4);
    int* row_start = (int*)alloc((size_t)(N + 1) * 4);
    int* cursor = (int*)alloc((size_t)N * 4);
    int* eidx = (int*)alloc((size_t)E * 4);
    float* A = (float*)alloc((size_t)4 * 64 * 128 * 4);
    float* B = (float*)alloc((size_t)4 * 64 * 128 * 4);
    float* ybr = (float*)alloc((size_t)4 * 128 * 4);
    float* ybs = (float*)alloc((size_t)4 * 128 * 4);
    float* Wfold = (float*)alloc((size_t)64 * 712 * 4);
    float* biasrow = (float*)alloc((size_t)712 * 4);

    hipMemsetAsync(deg, 0, (size_t)N * 4, stream);
    k0a_kernel<<<256, 256, 0, stream>>>(W_node, Wk_s, Wk_r, A, B);
    k0a2_kernel<<<4, 256, 0, stream>>>(b_node, Wk_s, Wk_r, bk_s, bk_r, ybs, ybr);
    k0b_kernel<<<(65 * 712 + 255) / 256, 256, 0, stream>>>(W_node, b_node, A, B, ybr, ybs,
                                                           Wk_s, W_edge, bk_s, b_edge, Wfold,
                                                           biasrow);
    dim3 g1grid((N + 63) / 64, 12);
    g1_kernel<<<g1grid, 256, 0, stream>>>(nodes, Wfold, biasrow, T, S, N);
    hist_kernel<<<(E + 255) / 256, 256, 0, stream>>>(receivers, deg, E);
    scan_kernel<<<1, 1024, 0, stream>>>(deg, row_start, cursor, N);
    scatter_kernel<<<(E + 255) / 256, 256, 0, stream>>>(receivers, cursor, eidx, E);
    en_kernel<<<(N + 3) / 4, 256, 0, stream>>>(row_start, eidx, senders, edges, T, S, W_edge,
                                               b_edge, agg, N);
    g3_kernel<<<(N + 31) / 32, 256, 0, stream>>>(T, agg, W_out, b_out, avgflag, outp, N);
}

// Round 2
// 551.539 us; speedup vs baseline: 1.9076x; 1.9076x over previous
//
#include <hip/hip_runtime.h>

typedef unsigned short u16;
typedef unsigned int u32;
typedef short bh8 __attribute__((ext_vector_type(8)));   // 8 bf16 (A/B frag)
typedef float f4 __attribute__((ext_vector_type(4)));    // 4 f32 (C/D frag)

__device__ __forceinline__ float bf2f(u16 h) { return __uint_as_float(((u32)h) << 16); }
__device__ __forceinline__ float bflo(u32 u) { return __uint_as_float(u << 16); }
__device__ __forceinline__ float bfhi(u32 u) { return __uint_as_float(u & 0xffff0000u); }
__device__ __forceinline__ u16 f2bf(float f) {
    u32 x = __float_as_uint(f);
    return (u16)((x + 0x7fffu + ((x >> 16) & 1u)) >> 16);  // RNE
}

// ---------------- K0a: A_h = W_node @ Wk_r[h], B_h = W_node @ Wk_s[h] ----------------
__global__ void k0a_kernel(const float* __restrict__ Wn, const float* __restrict__ Wks,
                           const float* __restrict__ Wkr, float* __restrict__ A,
                           float* __restrict__ B) {
    int idx = blockIdx.x * 256 + threadIdx.x;  // 2*4*64*128 = 65536
    if (idx >= 65536) return;
    int which = idx >> 15;
    int rem = idx & 32767;
    int h = rem >> 13;
    int r = rem & 8191;
    int a = r >> 7, dp = r & 127;
    const float* W = which ? Wks : Wkr;
    float acc = 0.f;
    for (int d = 0; d < 128; ++d)
        acc += Wn[a * 128 + d] * W[(h * 128 + d) * 128 + dp];
    (which ? B : A)[(h * 64 + a) * 128 + dp] = acc;
}

// ---------------- K0a2: ybr_h = b_node@Wk_r[h] + bk_r[h]; ybs_h likewise with s ------
__global__ void k0a2_kernel(const float* __restrict__ bn, const float* __restrict__ Wks,
                            const float* __restrict__ Wkr, const float* __restrict__ bks,
                            const float* __restrict__ bkr, float* __restrict__ ybs,
                            float* __restrict__ ybr) {
    int idx = blockIdx.x * 256 + threadIdx.x;  // 2*4*128 = 1024
    if (idx >= 1024) return;
    int which = idx >> 9;
    int rem = idx & 511;
    int h = rem >> 7, dp = rem & 127;
    const float* W = which ? Wks : Wkr;
    const float* b = which ? bks : bkr;
    float acc = b[h * 128 + dp];
    for (int d = 0; d < 128; ++d) acc += bn[d] * W[(h * 128 + d) * 128 + dp];
    (which ? ybs : ybr)[h * 128 + dp] = acc;
}

// ---------------- K0b: assemble Wfold [64 x 712] + biasrow[712] ----------------------
// cols: [0:128) x | [128:640) v(h,i) | [640:704) u stored K-MAJOR: 640+k*4+h | [704:712) d0/c0
__global__ void k0b_kernel(const float* __restrict__ Wn, const float* __restrict__ bn,
                           const float* __restrict__ A, const float* __restrict__ B,
                           const float* __restrict__ ybr, const float* __restrict__ ybs,
                           const float* __restrict__ Wks, const float* __restrict__ Wedge,
                           const float* __restrict__ bks, const float* __restrict__ bedge,
                           float* __restrict__ Wfold, float* __restrict__ biasrow) {
    int idx = blockIdx.x * 256 + threadIdx.x;  // 65*712
    if (idx >= 65 * 712) return;
    int a = idx / 712, c = idx % 712;
    float val;
    if (c < 128) {
        val = (a < 64) ? Wn[a * 128 + c] : bn[c];
    } else if (c < 640) {
        int h = (c - 128) >> 7, i = (c - 128) & 127;
        const float* rv = (a < 64) ? &A[(h * 64 + a) * 128] : &ybr[h * 128];
        float s = 0.f;
        for (int d = 0; d < 128; ++d) s += rv[d] * Wks[(h * 128 + i) * 128 + d];
        val = s;
    } else if (c < 704) {
        int k = (c - 640) >> 2, h = (c - 640) & 3;  // k-major so en loads 4 heads per 8B
        const float* rv = (a < 64) ? &B[(h * 64 + a) * 128] : &ybs[h * 128];
        float s = 0.f;
        for (int d = 0; d < 128; ++d) s += rv[d] * Wedge[k * 128 + d];
        val = s;
    } else if (c < 708) {
        int h = c - 704;
        const float* rv = (a < 64) ? &A[(h * 64 + a) * 128] : &ybr[h * 128];
        float s = 0.f;
        for (int d = 0; d < 128; ++d) s += rv[d] * bks[h * 128 + d];
        val = s;
    } else {
        int h = c - 708;
        const float* rv = (a < 64) ? &B[(h * 64 + a) * 128] : &ybs[h * 128];
        float s = 0.f;
        for (int d = 0; d < 128; ++d) s += rv[d] * bedge[d];
        val = s;
    }
    if (a < 64) Wfold[(size_t)a * 712 + c] = val;
    else biasrow[c] = val;
}

// ---------------- wconv: bf16 transposed copies of Wfold and W_out -------------------
// WfT[c][k]: 768x64 (cols >=712 zero);  WoT[c][k]: 128x512
__global__ void wconv_kernel(const float* __restrict__ Wfold, const float* __restrict__ Wout,
                             u16* __restrict__ WfT, u16* __restrict__ WoT) {
    int i = blockIdx.x * 256 + threadIdx.x;
    if (i < 768 * 64) {
        int c = i >> 6, k = i & 63;
        WfT[i] = f2bf(c < 712 ? Wfold[(size_t)k * 712 + c] : 0.f);
    }
    int j = i - 768 * 64;
    if (j >= 0 && j < 128 * 512) {
        int c = j >> 9, k = j & 511;
        WoT[j] = f2bf(Wout[(size_t)k * 128 + c]);
    }
}

// ---------------- G1 (MFMA): T[N,704](bf16), S[N,8](f32) = nodes[N,64] @ Wfold -------
__global__ __launch_bounds__(256) void g1_kernel(const float* __restrict__ nodes,
                                                 const u16* __restrict__ WfT,
                                                 const float* __restrict__ biasrow,
                                                 u16* __restrict__ T, float* __restrict__ S,
                                                 int N) {
    __shared__ u16 Asm[64][72];
    __shared__ u16 Bsm[128][72];
    int t = threadIdx.x;
    int r0 = blockIdx.x * 64, c0 = blockIdx.y * 128;
    {  // stage A: 64 rows x 64 k, f32 -> bf16
        int row = t >> 2, cb = (t & 3) * 16;
        int r = r0 + row;
        u16 pk[16];
        if (r < N) {
            const float* src = &nodes[(size_t)r * 64 + cb];
#pragma unroll
            for (int q = 0; q < 16; ++q) pk[q] = f2bf(src[q]);
        } else {
#pragma unroll
            for (int q = 0; q < 16; ++q) pk[q] = 0;
        }
        *(uint4*)&Asm[row][cb] = *(const uint4*)&pk[0];
        *(uint4*)&Asm[row][cb + 8] = *(const uint4*)&pk[8];
    }
    {  // stage B (pre-transposed [col][k]): 128 cols x 64 k
        int col = t >> 1, ks = (t & 1) * 32;
        const u16* src = &WfT[(size_t)(c0 + col) * 64 + ks];
        uint4 v0 = *(const uint4*)src;
        uint4 v1 = *(const uint4*)(src + 8);
        uint4 v2 = *(const uint4*)(src + 16);
        uint4 v3 = *(const uint4*)(src + 24);
        *(uint4*)&Bsm[col][ks] = v0;
        *(uint4*)&Bsm[col][ks + 8] = v1;
        *(uint4*)&Bsm[col][ks + 16] = v2;
        *(uint4*)&Bsm[col][ks + 24] = v3;
    }
    __syncthreads();
    int lane = t & 63, wave = t >> 6;
    int wm = wave >> 1, wn = wave & 1;
    int lr = lane & 15, lk = lane >> 4;
    f4 acc[2][4] = {};
#pragma unroll
    for (int kk = 0; kk < 2; ++kk) {
        bh8 a[2], b[4];
#pragma unroll
        for (int am = 0; am < 2; ++am)
            a[am] = *(const bh8*)&Asm[wm * 32 + am * 16 + lr][kk * 32 + lk * 8];
#pragma unroll
        for (int bn = 0; bn < 4; ++bn)
            b[bn] = *(const bh8*)&Bsm[wn * 64 + bn * 16 + lr][kk * 32 + lk * 8];
#pragma unroll
        for (int am = 0; am < 2; ++am)
#pragma unroll
            for (int bn = 0; bn < 4; ++bn)
                acc[am][bn] = __builtin_amdgcn_mfma_f32_16x16x32_bf16(a[am], b[bn], acc[am][bn], 0, 0, 0);
    }
#pragma unroll
    for (int am = 0; am < 2; ++am)
#pragma unroll
        for (int bn = 0; bn < 4; ++bn) {
            int c = c0 + wn * 64 + bn * 16 + lr;
            if (c < 712) {
                float brow = biasrow[c];
#pragma unroll
                for (int q = 0; q < 4; ++q) {
                    int r = r0 + wm * 32 + am * 16 + lk * 4 + q;
                    if (r < N) {
                        float val = acc[am][bn][q] + brow;
                        if (c < 704) T[(size_t)r * 704 + c] = f2bf(val);
                        else S[(size_t)r * 8 + (c - 704)] = val;
                    }
                }
            }
        }
}

// ---------------- CSR build ----------------------------------------------------------
__global__ void hist_kernel(const int* __restrict__ recv, int* __restrict__ deg, int E) {
    int e = blockIdx.x * 256 + threadIdx.x;
    if (e < E) atomicAdd(&deg[recv[e]], 1);
}

__global__ __launch_bounds__(1024) void scan_kernel(const int* __restrict__ deg,
                                                    int* __restrict__ row_start,
                                                    int* __restrict__ cursor, int N) {
    __shared__ int sm[1024];
    int t = threadIdx.x;
    int C = (N + 1023) >> 10;
    int base = t * C;
    int s = 0;
    for (int i = 0; i < C; ++i) {
        int idx = base + i;
        if (idx < N) s += deg[idx];
    }
    sm[t] = s;
    __syncthreads();
    for (int off = 1; off < 1024; off <<= 1) {
        int v = (t >= off) ? sm[t - off] : 0;
        __syncthreads();
        sm[t] += v;
        __syncthreads();
    }
    int run = (t == 0) ? 0 : sm[t - 1];
    for (int i = 0; i < C; ++i) {
        int idx = base + i;
        if (idx < N) {
            row_start[idx] = run;
            cursor[idx] = run;
            run += deg[idx];
        }
    }
    if (t == 1023) row_start[N] = sm[1023];
}

__global__ void scatter_kernel(const int* __restrict__ recv, int* __restrict__ cursor,
                               int* __restrict__ eidx, int E) {
    int e = blockIdx.x * 256 + threadIdx.x;
    if (e < E) {
        int p = atomicAdd(&cursor[recv[e]], 1);
        eidx[p] = e;
    }
}

// ---------------- EN v2: online softmax, 4 edges/wave in parallel, single x read -----
// Wave = 1 node. Lane = (g,k16): group g handles edge chunk*4+g; k16 spans 8 channels.
// agg_h = [ accX_h + accE_h @ W_edge ] / S_h + b_edge   (since sum of weights = 1)
__global__ __launch_bounds__(256) void en_kernel(const int* __restrict__ row_start,
                                                 const int* __restrict__ eidx,
                                                 const int* __restrict__ senders,
                                                 const float* __restrict__ edges,
                                                 const u16* __restrict__ T,
                                                 const float* __restrict__ S,
                                                 const float* __restrict__ W_edge,
                                                 const float* __restrict__ b_edge,
                                                 u16* __restrict__ agg, int N) {
    int t = threadIdx.x;
    int wid = t >> 6, lane = t & 63;
    int g = lane >> 4, k16 = lane & 15;
    int n = blockIdx.x * 4 + wid;
    if (n >= N) return;
    int rs = row_start[n];
    int deg = row_start[n + 1] - rs;

    const u16* Tr = T + (size_t)n * 704;
    uint4 vreg[4];
#pragma unroll
    for (int h = 0; h < 4; ++h) vreg[h] = *(const uint4*)(Tr + 128 + h * 128 + 8 * k16);
    float4 d0 = *(const float4*)&S[(size_t)n * 8];
    float dd[4] = {d0.x, d0.y, d0.z, d0.w};

    float m[4] = {-1e30f, -1e30f, -1e30f, -1e30f};
    float Ss[4] = {0.f, 0.f, 0.f, 0.f};
    float aX[4][8] = {};
    float aE[4] = {0.f, 0.f, 0.f, 0.f};

    if (deg > 0) {
        int nch = (deg + 3) >> 2;
        int eC, sC, eN, sN;
        {
            int ev = 0, sv = 0;
            if (lane < 4) {
                int jj = lane; if (jj >= deg) jj = deg - 1;
                ev = eidx[rs + jj]; sv = senders[ev];
            }
            eC = __shfl(ev, g); sC = __shfl(sv, g);
        }
        const u16* Ts0 = T + (size_t)sC * 704;
        uint4 xq = *(const uint4*)(Ts0 + 8 * k16);
        uint2 uq = *(const uint2*)(Ts0 + 640 + 4 * k16);
        float eq = edges[(size_t)eC * 16 + k16];
        float4 cq = *(const float4*)&S[(size_t)sC * 8 + 4];
        if (nch > 1) {
            int ev = 0, sv = 0;
            if (lane < 4) {
                int jj = 4 + lane; if (jj >= deg) jj = deg - 1;
                ev = eidx[rs + jj]; sv = senders[ev];
            }
            eN = __shfl(ev, g); sN = __shfl(sv, g);
        } else { eN = eC; sN = sC; }

        for (int c = 0; c < nch; ++c) {
            uint4 xu = xq; uint2 uc = uq; float ecv = eq; float4 ccv = cq;
            bool act = (c * 4 + g) < deg;
            eC = eN; sC = sN;
            if (c + 1 < nch) {  // prefetch next chunk's payload
                const u16* Ts = T + (size_t)sC * 704;
                xq = *(const uint4*)(Ts + 8 * k16);
                uq = *(const uint2*)(Ts + 640 + 4 * k16);
                eq = edges[(size_t)eC * 16 + k16];
                cq = *(const float4*)&S[(size_t)sC * 8 + 4];
                if (c + 2 < nch) {  // prefetch chunk-after-next's indices
                    int ev = 0, sv = 0;
                    if (lane < 4) {
                        int jj = (c + 2) * 4 + lane; if (jj >= deg) jj = deg - 1;
                        ev = eidx[rs + jj]; sv = senders[ev];
                    }
                    eN = __shfl(ev, g); sN = __shfl(sv, g);
                }
            }
            // unpack x (8 channels, reused for logit dot AND message)
            float X[8] = {bflo(xu.x), bfhi(xu.x), bflo(xu.y), bfhi(xu.y),
                          bflo(xu.z), bfhi(xu.z), bflo(xu.w), bfhi(xu.w)};
            float uh[4] = {bflo(uc.x), bfhi(uc.x), bflo(uc.y), bfhi(uc.y)};
            float cf[4] = {ccv.x, ccv.y, ccv.z, ccv.w};
            float lg[4];
#pragma unroll
            for (int h = 0; h < 4; ++h) {
                uint4 v = vreg[h];
                float p = ecv * uh[h];
                p += X[0] * bflo(v.x) + X[1] * bfhi(v.x);
                p += X[2] * bflo(v.y) + X[3] * bfhi(v.y);
                p += X[4] * bflo(v.z) + X[5] * bfhi(v.z);
                p += X[6] * bflo(v.w) + X[7] * bfhi(v.w);
                p += __shfl_xor(p, 8); p += __shfl_xor(p, 4);
                p += __shfl_xor(p, 2); p += __shfl_xor(p, 1);
                lg[h] = act ? 0.08838834764831843f * (p + dd[h] + cf[h]) : -1e30f;
            }
#pragma unroll
            for (int h = 0; h < 4; ++h) {
                float cm = fmaxf(lg[h], __shfl_xor(lg[h], 16));
                cm = fmaxf(cm, __shfl_xor(cm, 32));
                float nm = fmaxf(m[h], cm);
                float f = __expf(m[h] - nm);
                m[h] = nm;
                float wh = __expf(lg[h] - nm);  // inactive: exp(-1e30-nm)=0
                float ws = wh + __shfl_xor(wh, 16);
                ws += __shfl_xor(ws, 32);
                Ss[h] = Ss[h] * f + ws;
                aE[h] = aE[h] * f + wh * ecv;
#pragma unroll
                for (int i = 0; i < 8; ++i) aX[h][i] = fmaf(aX[h][i], f, wh * X[i]);
            }
        }
    }
    // cross-group reductions (sum over the 4 edge-groups)
#pragma unroll
    for (int h = 0; h < 4; ++h) {
#pragma unroll
        for (int i = 0; i < 8; ++i) {
            aX[h][i] += __shfl_xor(aX[h][i], 16);
            aX[h][i] += __shfl_xor(aX[h][i], 32);
        }
        aE[h] += __shfl_xor(aE[h], 16);
        aE[h] += __shfl_xor(aE[h], 32);
    }
    // each group finalizes head h = g
    float axg[8];
#pragma unroll
    for (int i = 0; i < 8; ++i)
        axg[i] = g == 0 ? aX[0][i] : g == 1 ? aX[1][i] : g == 2 ? aX[2][i] : aX[3][i];
    float aEsel = g == 0 ? aE[0] : g == 1 ? aE[1] : g == 2 ? aE[2] : aE[3];
    float Sg = g == 0 ? Ss[0] : g == 1 ? Ss[1] : g == 2 ? Ss[2] : Ss[3];
#pragma unroll
    for (int k = 0; k < 16; ++k) {
        float a = __shfl(aEsel, (g << 4) | k);  // source lane within same group
        float4 w0 = *(const float4*)&W_edge[k * 128 + 8 * k16];
        float4 w1 = *(const float4*)&W_edge[k * 128 + 8 * k16 + 4];
        axg[0] += a * w0.x; axg[1] += a * w0.y; axg[2] += a * w0.z; axg[3] += a * w0.w;
        axg[4] += a * w1.x; axg[5] += a * w1.y; axg[6] += a * w1.z; axg[7] += a * w1.w;
    }
    float inv = (deg > 0 && Sg > 0.f) ? 1.f / Sg : 0.f;
    float bes = (deg > 0) ? 1.f : 0.f;
    float4 b0 = *(const float4*)&b_edge[8 * k16];
    float4 b1 = *(const float4*)&b_edge[8 * k16 + 4];
    float r_[8];
    r_[0] = axg[0] * inv + bes * b0.x; r_[1] = axg[1] * inv + bes * b0.y;
    r_[2] = axg[2] * inv + bes * b0.z; r_[3] = axg[3] * inv + bes * b0.w;
    r_[4] = axg[4] * inv + bes * b1.x; r_[5] = axg[5] * inv + bes * b1.y;
    r_[6] = axg[6] * inv + bes * b1.z; r_[7] = axg[7] * inv + bes * b1.w;
    u32 o0 = (u32)f2bf(r_[0]) | ((u32)f2bf(r_[1]) << 16);
    u32 o1 = (u32)f2bf(r_[2]) | ((u32)f2bf(r_[3]) << 16);
    u32 o2 = (u32)f2bf(r_[4]) | ((u32)f2bf(r_[5]) << 16);
    u32 o3 = (u32)f2bf(r_[6]) | ((u32)f2bf(r_[7]) << 16);
    uint4 st = {o0, o1, o2, o3};
    *(uint4*)(agg + (size_t)n * 512 + g * 128 + 8 * k16) = st;
}

// ---------------- G3 (MFMA): out = relu(x + agg @ W_out + b_out) ---------------------
__global__ __launch_bounds__(256) void g3_kernel(const u16* __restrict__ T,
                                                 const u16* __restrict__ agg,
                                                 const u16* __restrict__ WoT,
                                                 const float* __restrict__ bout,
                                                 const int* __restrict__ avgflag,
                                                 float* __restrict__ out, int N) {
    int t = threadIdx.x;
    int r0 = blockIdx.x * 64;
    if (*avgflag) {
        for (int i = t; i < 64 * 128; i += 256) {
            int n = r0 + (i >> 7), j = i & 127;
            if (n < N) {
                float s = 0.f;
#pragma unroll
                for (int h = 0; h < 4; ++h) s += bf2f(agg[(size_t)n * 512 + h * 128 + j]);
                float v = bf2f(T[(size_t)n * 704 + j]) + 0.25f * s;
                out[(size_t)n * 128 + j] = v > 0.f ? v : 0.f;
            }
        }
        return;
    }
    __shared__ u16 Asm[64][72];
    __shared__ u16 Bsm[128][72];
    int lane = t & 63, wave = t >> 6;
    int wm = wave >> 1, wn = wave & 1;
    int lr = lane & 15, lk = lane >> 4;
    f4 acc[2][4] = {};
    for (int kb = 0; kb < 8; ++kb) {
        if (kb) __syncthreads();
        {  // stage A: agg (bf16) rows r0..+64, k = kb*64..
            int row = t >> 2, ks = (t & 3) * 16;
            int r = r0 + row;
            uint4 v0 = {0, 0, 0, 0}, v1 = {0, 0, 0, 0};
            if (r < N) {
                const u16* src = &agg[(size_t)r * 512 + kb * 64 + ks];
                v0 = *(const uint4*)src;
                v1 = *(const uint4*)(src + 8);
            }
            *(uint4*)&Asm[row][ks] = v0;
            *(uint4*)&Asm[row][ks + 8] = v1;
        }
        {  // stage B: WoT [col][k]
            int col = t >> 1, ks = (t & 1) * 32;
            const u16* src = &WoT[(size_t)col * 512 + kb * 64 + ks];
            uint4 v0 = *(const uint4*)src;
            uint4 v1 = *(const uint4*)(src + 8);
            uint4 v2 = *(const uint4*)(src + 16);
            uint4 v3 = *(const uint4*)(src + 24);
            *(uint4*)&Bsm[col][ks] = v0;
            *(uint4*)&Bsm[col][ks + 8] = v1;
            *(uint4*)&Bsm[col][ks + 16] = v2;
            *(uint4*)&Bsm[col][ks + 24] = v3;
        }
        __syncthreads();
#pragma unroll
        for (int kk = 0; kk < 2; ++kk) {
            bh8 a[2], b[4];
#pragma unroll
            for (int am = 0; am < 2; ++am)
                a[am] = *(const bh8*)&Asm[wm * 32 + am * 16 + lr][kk * 32 + lk * 8];
#pragma unroll
            for (int bn = 0; bn < 4; ++bn)
                b[bn] = *(const bh8*)&Bsm[wn * 64 + bn * 16 + lr][kk * 32 + lk * 8];
#pragma unroll
            for (int am = 0; am < 2; ++am)
#pragma unroll
                for (int bn = 0; bn < 4; ++bn)
                    acc[am][bn] = __builtin_amdgcn_mfma_f32_16x16x32_bf16(a[am], b[bn], acc[am][bn], 0, 0, 0);
        }
    }
#pragma unroll
    for (int am = 0; am < 2; ++am)
#pragma unroll
        for (int bn = 0; bn < 4; ++bn) {
            int c = wn * 64 + bn * 16 + lr;
            float bc = bout[c];
#pragma unroll
            for (int q = 0; q < 4; ++q) {
                int r = r0 + wm * 32 + am * 16 + lk * 4 + q;
                if (r < N) {
                    float v = acc[am][bn][q] + bc + bf2f(T[(size_t)r * 704 + c]);
                    out[(size_t)r * 128 + c] = v > 0.f ? v : 0.f;
                }
            }
        }
}

// ---------------- launch --------------------------------------------------------------
extern "C" void kernel_launch(void* const* d_in, const int* in_sizes, int n_in, void* d_out,
                              int out_size, void* d_ws, size_t ws_size, hipStream_t stream) {
    const float* nodes = (const float*)d_in[0];
    const float* edges = (const float*)d_in[1];
    const int* senders = (const int*)d_in[2];
    const int* receivers = (const int*)d_in[3];
    const int* avgflag = (const int*)d_in[4];
    const float* W_node = (const float*)d_in[5];
    const float* b_node = (const float*)d_in[6];
    const float* W_edge = (const float*)d_in[7];
    const float* b_edge = (const float*)d_in[8];
    const float* Wk_s = (const float*)d_in[9];
    const float* bk_s = (const float*)d_in[10];
    const float* Wk_r = (const float*)d_in[11];
    const float* bk_r = (const float*)d_in[12];
    const float* W_out = (const float*)d_in[13];
    const float* b_out = (const float*)d_in[14];
    int N = in_sizes[0] / 64;
    int E = in_sizes[2];
    float* outp = (float*)d_out;

    char* base = (char*)d_ws;
    size_t off = 0;
    auto alloc = [&](size_t nbytes) -> char* {
        char* p = base + off;
        off = (off + nbytes + 255) & ~(size_t)255;
        return p;
    };
    u16* T = (u16*)alloc((size_t)N * 704 * 2);
    float* S = (float*)alloc((size_t)N * 8 * 4);
    u16* agg = (u16*)alloc((size_t)N * 512 * 2);
    int* deg = (int*)alloc((size_t)N * 4);
    int* row_start = (int*)alloc((size_t)(N + 1) * 4);
    int* cursor = (int*)alloc((size_t)N * 4);
    int* eidx = (int*)alloc((size_t)E * 4);
    float* A = (float*)alloc((size_t)4 * 64 * 128 * 4);
    float* B = (float*)alloc((size_t)4 * 64 * 128 * 4);
    float* ybr = (float*)alloc((size_t)4 * 128 * 4);
    float* ybs = (float*)alloc((size_t)4 * 128 * 4);
    float* Wfold = (float*)alloc((size_t)64 * 712 * 4);
    float* biasrow = (float*)alloc((size_t)712 * 4);
    u16* WfT = (u16*)alloc((size_t)768 * 64 * 2);
    u16* WoT = (u16*)alloc((size_t)128 * 512 * 2);

    hipMemsetAsync(deg, 0, (size_t)N * 4, stream);
    k0a_kernel<<<256, 256, 0, stream>>>(W_node, Wk_s, Wk_r, A, B);
    k0a2_kernel<<<4, 256, 0, stream>>>(b_node, Wk_s, Wk_r, bk_s, bk_r, ybs, ybr);
    k0b_kernel<<<(65 * 712 + 255) / 256, 256, 0, stream>>>(W_node, b_node, A, B, ybr, ybs,
                                                           Wk_s, W_edge, bk_s, b_edge, Wfold,
                                                           biasrow);
    wconv_kernel<<<(768 * 64 + 128 * 512 + 255) / 256, 256, 0, stream>>>(Wfold, W_out, WfT, WoT);
    dim3 g1grid((N + 63) / 64, 6);
    g1_kernel<<<g1grid, 256, 0, stream>>>(nodes, WfT, biasrow, T, S, N);
    hist_kernel<<<(E + 255) / 256, 256, 0, stream>>>(receivers, deg, E);
    scan_kernel<<<1, 1024, 0, stream>>>(deg, row_start, cursor, N);
    scatter_kernel<<<(E + 255) / 256, 256, 0, stream>>>(receivers, cursor, eidx, E);
    en_kernel<<<(N + 3) / 4, 256, 0, stream>>>(row_start, eidx, senders, edges, T, S, W_edge,
                                               b_edge, agg, N);
    g3_kernel<<<(N + 63) / 64, 256, 0, stream>>>(T, agg, WoT, b_out, avgflag, outp, N);
}

// Round 3
// 525.008 us; speedup vs baseline: 2.0040x; 1.0505x over previous
//
#include <hip/hip_runtime.h>

typedef unsigned short u16;
typedef unsigned int u32;
typedef short bh8 __attribute__((ext_vector_type(8)));   // 8 bf16 (A/B frag)
typedef float f4 __attribute__((ext_vector_type(4)));    // 4 f32 (C/D frag)
typedef float pf2 __attribute__((ext_vector_type(2)));   // packed f32 pair

__device__ __forceinline__ float bf2f(u16 h) { return __uint_as_float(((u32)h) << 16); }
__device__ __forceinline__ float bflo(u32 u) { return __uint_as_float(u << 16); }
__device__ __forceinline__ float bfhi(u32 u) { return __uint_as_float(u & 0xffff0000u); }
__device__ __forceinline__ u16 f2bf(float f) {
    u32 x = __float_as_uint(f);
    return (u16)((x + 0x7fffu + ((x >> 16) & 1u)) >> 16);  // RNE
}
__device__ __forceinline__ pf2 pkfma(pf2 a, pf2 b, pf2 c) {
    pf2 d;
    asm("v_pk_fma_f32 %0, %1, %2, %3" : "=v"(d) : "v"(a), "v"(b), "v"(c));
    return d;
}
__device__ __forceinline__ pf2 u2f2(u32 u) {
    pf2 r;
    r.x = bflo(u);
    r.y = bfhi(u);
    return r;
}

// ---------------- K0a: A_h = W_node @ Wk_r[h], B_h = W_node @ Wk_s[h] ----------------
__global__ void k0a_kernel(const float* __restrict__ Wn, const float* __restrict__ Wks,
                           const float* __restrict__ Wkr, float* __restrict__ A,
                           float* __restrict__ B) {
    int idx = blockIdx.x * 256 + threadIdx.x;  // 2*4*64*128 = 65536
    if (idx >= 65536) return;
    int which = idx >> 15;
    int rem = idx & 32767;
    int h = rem >> 13;
    int r = rem & 8191;
    int a = r >> 7, dp = r & 127;
    const float* W = which ? Wks : Wkr;
    float acc = 0.f;
    for (int d = 0; d < 128; ++d)
        acc += Wn[a * 128 + d] * W[(h * 128 + d) * 128 + dp];
    (which ? B : A)[(h * 64 + a) * 128 + dp] = acc;
}

// ---------------- K0a2: ybr_h = b_node@Wk_r[h] + bk_r[h]; ybs_h likewise with s ------
__global__ void k0a2_kernel(const float* __restrict__ bn, const float* __restrict__ Wks,
                            const float* __restrict__ Wkr, const float* __restrict__ bks,
                            const float* __restrict__ bkr, float* __restrict__ ybs,
                            float* __restrict__ ybr) {
    int idx = blockIdx.x * 256 + threadIdx.x;  // 2*4*128 = 1024
    if (idx >= 1024) return;
    int which = idx >> 9;
    int rem = idx & 511;
    int h = rem >> 7, dp = rem & 127;
    const float* W = which ? Wks : Wkr;
    const float* b = which ? bks : bkr;
    float acc = b[h * 128 + dp];
    for (int d = 0; d < 128; ++d) acc += bn[d] * W[(h * 128 + d) * 128 + dp];
    (which ? ybs : ybr)[h * 128 + dp] = acc;
}

// ---------------- K0b: assemble Wfold [64 x 708] + biasrow[708] ----------------------
// cols: [0:128) x | [128:640) v(h,i) | [640:704) u k-major: 640+k*4+h | [704:708) c0_h
// (d0 receiver-constant dropped: cancels in softmax)
__global__ void k0b_kernel(const float* __restrict__ Wn, const float* __restrict__ bn,
                           const float* __restrict__ A, const float* __restrict__ B,
                           const float* __restrict__ ybr, const float* __restrict__ ybs,
                           const float* __restrict__ Wks, const float* __restrict__ Wedge,
                           const float* __restrict__ bks, const float* __restrict__ bedge,
                           float* __restrict__ Wfold, float* __restrict__ biasrow) {
    int idx = blockIdx.x * 256 + threadIdx.x;  // 65*708
    if (idx >= 65 * 708) return;
    int a = idx / 708, c = idx % 708;
    float val;
    if (c < 128) {
        val = (a < 64) ? Wn[a * 128 + c] : bn[c];
    } else if (c < 640) {
        int h = (c - 128) >> 7, i = (c - 128) & 127;
        const float* rv = (a < 64) ? &A[(h * 64 + a) * 128] : &ybr[h * 128];
        float s = 0.f;
        for (int d = 0; d < 128; ++d) s += rv[d] * Wks[(h * 128 + i) * 128 + d];
        val = s;
    } else if (c < 704) {
        int k = (c - 640) >> 2, h = (c - 640) & 3;  // k-major so en loads 4 heads per 8B
        const float* rv = (a < 64) ? &B[(h * 64 + a) * 128] : &ybs[h * 128];
        float s = 0.f;
        for (int d = 0; d < 128; ++d) s += rv[d] * Wedge[k * 128 + d];
        val = s;
    } else {
        int h = c - 704;
        const float* rv = (a < 64) ? &B[(h * 64 + a) * 128] : &ybs[h * 128];
        float s = 0.f;
        for (int d = 0; d < 128; ++d) s += rv[d] * bedge[d];
        val = s;
    }
    if (a < 64) Wfold[(size_t)a * 708 + c] = val;
    else biasrow[c] = val;
}

// ---------------- wconv: bf16 transposed copies of Wfold and W_out -------------------
// WfT[c][k]: 768x64 (cols >=708 zero);  WoT[c][k]: 128x512
__global__ void wconv_kernel(const float* __restrict__ Wfold, const float* __restrict__ Wout,
                             u16* __restrict__ WfT, u16* __restrict__ WoT) {
    int i = blockIdx.x * 256 + threadIdx.x;
    if (i < 768 * 64) {
        int c = i >> 6, k = i & 63;
        WfT[i] = f2bf(c < 708 ? Wfold[(size_t)k * 708 + c] : 0.f);
    }
    int j = i - 768 * 64;
    if (j >= 0 && j < 128 * 512) {
        int c = j >> 9, k = j & 511;
        WoT[j] = f2bf(Wout[(size_t)k * 128 + c]);
    }
}

// ---------------- G1 (MFMA): T[N,704](bf16), S[N,4](f32) = nodes[N,64] @ Wfold -------
__global__ __launch_bounds__(256) void g1_kernel(const float* __restrict__ nodes,
                                                 const u16* __restrict__ WfT,
                                                 const float* __restrict__ biasrow,
                                                 u16* __restrict__ T, float* __restrict__ S,
                                                 int N) {
    __shared__ u16 Asm[64][72];
    __shared__ u16 Bsm[128][72];
    int t = threadIdx.x;
    int r0 = blockIdx.x * 64, c0 = blockIdx.y * 128;
    {  // stage A: 64 rows x 64 k, f32 -> bf16
        int row = t >> 2, cb = (t & 3) * 16;
        int r = r0 + row;
        u16 pk[16];
        if (r < N) {
            const float* src = &nodes[(size_t)r * 64 + cb];
#pragma unroll
            for (int q = 0; q < 16; ++q) pk[q] = f2bf(src[q]);
        } else {
#pragma unroll
            for (int q = 0; q < 16; ++q) pk[q] = 0;
        }
        *(uint4*)&Asm[row][cb] = *(const uint4*)&pk[0];
        *(uint4*)&Asm[row][cb + 8] = *(const uint4*)&pk[8];
    }
    {  // stage B (pre-transposed [col][k]): 128 cols x 64 k
        int col = t >> 1, ks = (t & 1) * 32;
        const u16* src = &WfT[(size_t)(c0 + col) * 64 + ks];
        uint4 v0 = *(const uint4*)src;
        uint4 v1 = *(const uint4*)(src + 8);
        uint4 v2 = *(const uint4*)(src + 16);
        uint4 v3 = *(const uint4*)(src + 24);
        *(uint4*)&Bsm[col][ks] = v0;
        *(uint4*)&Bsm[col][ks + 8] = v1;
        *(uint4*)&Bsm[col][ks + 16] = v2;
        *(uint4*)&Bsm[col][ks + 24] = v3;
    }
    __syncthreads();
    int lane = t & 63, wave = t >> 6;
    int wm = wave >> 1, wn = wave & 1;
    int lr = lane & 15, lk = lane >> 4;
    f4 acc[2][4] = {};
#pragma unroll
    for (int kk = 0; kk < 2; ++kk) {
        bh8 a[2], b[4];
#pragma unroll
        for (int am = 0; am < 2; ++am)
            a[am] = *(const bh8*)&Asm[wm * 32 + am * 16 + lr][kk * 32 + lk * 8];
#pragma unroll
        for (int bn = 0; bn < 4; ++bn)
            b[bn] = *(const bh8*)&Bsm[wn * 64 + bn * 16 + lr][kk * 32 + lk * 8];
#pragma unroll
        for (int am = 0; am < 2; ++am)
#pragma unroll
            for (int bn = 0; bn < 4; ++bn)
                acc[am][bn] = __builtin_amdgcn_mfma_f32_16x16x32_bf16(a[am], b[bn], acc[am][bn], 0, 0, 0);
    }
#pragma unroll
    for (int am = 0; am < 2; ++am)
#pragma unroll
        for (int bn = 0; bn < 4; ++bn) {
            int c = c0 + wn * 64 + bn * 16 + lr;
            if (c < 708) {
                float brow = biasrow[c];
#pragma unroll
                for (int q = 0; q < 4; ++q) {
                    int r = r0 + wm * 32 + am * 16 + lk * 4 + q;
                    if (r < N) {
                        float val = acc[am][bn][q] + brow;
                        if (c < 704) T[(size_t)r * 704 + c] = f2bf(val);
                        else S[(size_t)r * 4 + (c - 704)] = val;
                    }
                }
            }
        }
}

// ---------------- CSR build ----------------------------------------------------------
__global__ void hist_kernel(const int* __restrict__ recv, int* __restrict__ deg, int E) {
    int e = blockIdx.x * 256 + threadIdx.x;
    if (e < E) atomicAdd(&deg[recv[e]], 1);
}

__global__ __launch_bounds__(1024) void scan_kernel(const int* __restrict__ deg,
                                                    int* __restrict__ row_start,
                                                    int* __restrict__ cursor, int N) {
    __shared__ int sm[1024];
    int t = threadIdx.x;
    int C = (N + 1023) >> 10;
    int base = t * C;
    int s = 0;
    for (int i = 0; i < C; ++i) {
        int idx = base + i;
        if (idx < N) s += deg[idx];
    }
    sm[t] = s;
    __syncthreads();
    for (int off = 1; off < 1024; off <<= 1) {
        int v = (t >= off) ? sm[t - off] : 0;
        __syncthreads();
        sm[t] += v;
        __syncthreads();
    }
    int run = (t == 0) ? 0 : sm[t - 1];
    for (int i = 0; i < C; ++i) {
        int idx = base + i;
        if (idx < N) {
            row_start[idx] = run;
            cursor[idx] = run;
            run += deg[idx];
        }
    }
    if (t == 1023) row_start[N] = sm[1023];
}

__global__ void scatter_kernel(const int* __restrict__ recv, int* __restrict__ cursor,
                               int* __restrict__ eidx, int E) {
    int e = blockIdx.x * 256 + threadIdx.x;
    if (e < E) {
        int p = atomicAdd(&cursor[recv[e]], 1);
        eidx[p] = e;
    }
}

// ---------------- EN v3: no-max softmax (shift-invariant), pk_fma, grid-stride -------
// Wave = 1 node (strided). Lane = (g,k16): group g handles edge chunk*4+g; k16 = 8 ch.
// agg_h = [ Σw·x_s + (Σw·e) @ W_edge ] / Σw + b_edge
__global__ __launch_bounds__(256) void en_kernel(const int* __restrict__ row_start,
                                                 const int* __restrict__ eidx,
                                                 const int* __restrict__ senders,
                                                 const float* __restrict__ edges,
                                                 const u16* __restrict__ T,
                                                 const float* __restrict__ S,
                                                 const float* __restrict__ W_edge,
                                                 const float* __restrict__ b_edge,
                                                 u16* __restrict__ agg, int N) {
    __shared__ float Wl[16 * 128];
    int t = threadIdx.x;
    for (int i = t; i < 2048; i += 256) Wl[i] = W_edge[i];
    __syncthreads();
    int lane = t & 63, wid = t >> 6;
    int g = lane >> 4, k16 = lane & 15;
    int gw = blockIdx.x * 4 + wid;
    int GW = gridDim.x * 4;
    const float ksc = 0.08838834764831843f;

    for (int n = gw; n < N; n += GW) {
        int rs = row_start[n];
        int deg = row_start[n + 1] - rs;

        const u16* Tr = T + (size_t)n * 704;
        pf2 vreg[4][4];
#pragma unroll
        for (int h = 0; h < 4; ++h) {
            uint4 v = *(const uint4*)(Tr + 128 + h * 128 + 8 * k16);
            vreg[h][0] = u2f2(v.x); vreg[h][1] = u2f2(v.y);
            vreg[h][2] = u2f2(v.z); vreg[h][3] = u2f2(v.w);
        }
        pf2 aX[4][4] = {};
        float Ss[4] = {0.f, 0.f, 0.f, 0.f};
        float aE[4] = {0.f, 0.f, 0.f, 0.f};

        if (deg > 0) {
            int nch = (deg + 3) >> 2;
            int eC, sC, eN_, sN_;
            {
                int ev = 0, sv = 0;
                if (lane < 4) {
                    int jj = lane; if (jj >= deg) jj = deg - 1;
                    ev = eidx[rs + jj]; sv = senders[ev];
                }
                eC = __shfl(ev, g); sC = __shfl(sv, g);
            }
            uint4 xq; uint2 uq; float eq; float4 cq;
            {
                const u16* Ts = T + (size_t)sC * 704;
                xq = *(const uint4*)(Ts + 8 * k16);
                uq = *(const uint2*)(Ts + 640 + 4 * k16);
                eq = edges[(size_t)eC * 16 + k16];
                cq = *(const float4*)&S[(size_t)sC * 4];
            }
            if (nch > 1) {
                int ev = 0, sv = 0;
                if (lane < 4) {
                    int jj = 4 + lane; if (jj >= deg) jj = deg - 1;
                    ev = eidx[rs + jj]; sv = senders[ev];
                }
                eN_ = __shfl(ev, g); sN_ = __shfl(sv, g);
            } else { eN_ = eC; sN_ = sC; }

            for (int c = 0; c < nch; ++c) {
                uint4 xu = xq; uint2 uc = uq; float ecv = eq; float4 ccv = cq;
                bool act = (c * 4 + g) < deg;
                eC = eN_; sC = sN_;
                if (c + 1 < nch) {  // prefetch next chunk's payload
                    const u16* Ts = T + (size_t)sC * 704;
                    xq = *(const uint4*)(Ts + 8 * k16);
                    uq = *(const uint2*)(Ts + 640 + 4 * k16);
                    eq = edges[(size_t)eC * 16 + k16];
                    cq = *(const float4*)&S[(size_t)sC * 4];
                    if (c + 2 < nch) {  // prefetch chunk-after-next's indices
                        int ev = 0, sv = 0;
                        if (lane < 4) {
                            int jj = (c + 2) * 4 + lane; if (jj >= deg) jj = deg - 1;
                            ev = eidx[rs + jj]; sv = senders[ev];
                        }
                        eN_ = __shfl(ev, g); sN_ = __shfl(sv, g);
                    }
                }
                pf2 X[4] = {u2f2(xu.x), u2f2(xu.y), u2f2(xu.z), u2f2(xu.w)};
                float uh[4] = {bflo(uc.x), bfhi(uc.x), bflo(uc.y), bfhi(uc.y)};
                float cf[4] = {ccv.x, ccv.y, ccv.z, ccv.w};
#pragma unroll
                for (int h = 0; h < 4; ++h) {
                    pf2 p2 = {ecv * uh[h], 0.f};
                    p2 = pkfma(X[0], vreg[h][0], p2);
                    p2 = pkfma(X[1], vreg[h][1], p2);
                    p2 = pkfma(X[2], vreg[h][2], p2);
                    p2 = pkfma(X[3], vreg[h][3], p2);
                    float p = p2.x + p2.y;
                    p += __shfl_xor(p, 1); p += __shfl_xor(p, 2);
                    p += __shfl_xor(p, 4); p += __shfl_xor(p, 8);
                    float wh = act ? __expf(ksc * (p + cf[h])) : 0.f;
                    Ss[h] += wh;
                    aE[h] = fmaf(wh, ecv, aE[h]);
                    pf2 w2 = {wh, wh};
                    aX[h][0] = pkfma(w2, X[0], aX[h][0]);
                    aX[h][1] = pkfma(w2, X[1], aX[h][1]);
                    aX[h][2] = pkfma(w2, X[2], aX[h][2]);
                    aX[h][3] = pkfma(w2, X[3], aX[h][3]);
                }
            }
        }
        // butterfly sum across the 4 groups (xor16, xor32)
#pragma unroll
        for (int h = 0; h < 4; ++h) {
#pragma unroll
            for (int i = 0; i < 4; ++i) {
                pf2 v = aX[h][i], o;
                o.x = __shfl_xor(v.x, 16); o.y = __shfl_xor(v.y, 16);
                v += o;
                o.x = __shfl_xor(v.x, 32); o.y = __shfl_xor(v.y, 32);
                aX[h][i] = v + o;
            }
            Ss[h] += __shfl_xor(Ss[h], 16); Ss[h] += __shfl_xor(Ss[h], 32);
            aE[h] += __shfl_xor(aE[h], 16); aE[h] += __shfl_xor(aE[h], 32);
        }
        // group g finalizes head g
        pf2 axg[4];
#pragma unroll
        for (int i = 0; i < 4; ++i)
            axg[i] = g == 0 ? aX[0][i] : g == 1 ? aX[1][i] : g == 2 ? aX[2][i] : aX[3][i];
        float aEg = g == 0 ? aE[0] : g == 1 ? aE[1] : g == 2 ? aE[2] : aE[3];
        float Sg = g == 0 ? Ss[0] : g == 1 ? Ss[1] : g == 2 ? Ss[2] : Ss[3];
#pragma unroll
        for (int k = 0; k < 16; ++k) {
            float a = __shfl(aEg, (g << 4) | k);
            pf2 a2 = {a, a};
            const float* wr = &Wl[k * 128 + 8 * k16];
            axg[0] = pkfma(a2, *(const pf2*)(wr + 0), axg[0]);
            axg[1] = pkfma(a2, *(const pf2*)(wr + 2), axg[1]);
            axg[2] = pkfma(a2, *(const pf2*)(wr + 4), axg[2]);
            axg[3] = pkfma(a2, *(const pf2*)(wr + 6), axg[3]);
        }
        float inv = (deg > 0 && Sg > 0.f) ? 1.f / Sg : 0.f;
        float bes = (deg > 0) ? 1.f : 0.f;
        const float* br = &b_edge[8 * k16];
        float r_[8];
#pragma unroll
        for (int i = 0; i < 4; ++i) {
            r_[2 * i] = axg[i].x * inv + bes * br[2 * i];
            r_[2 * i + 1] = axg[i].y * inv + bes * br[2 * i + 1];
        }
        u32 o0 = (u32)f2bf(r_[0]) | ((u32)f2bf(r_[1]) << 16);
        u32 o1 = (u32)f2bf(r_[2]) | ((u32)f2bf(r_[3]) << 16);
        u32 o2 = (u32)f2bf(r_[4]) | ((u32)f2bf(r_[5]) << 16);
        u32 o3 = (u32)f2bf(r_[6]) | ((u32)f2bf(r_[7]) << 16);
        uint4 st = {o0, o1, o2, o3};
        *(uint4*)(agg + (size_t)n * 512 + g * 128 + 8 * k16) = st;
    }
}

// ---------------- G3 (MFMA): out = relu(x + agg @ W_out + b_out) ---------------------
__global__ __launch_bounds__(256) void g3_kernel(const u16* __restrict__ T,
                                                 const u16* __restrict__ agg,
                                                 const u16* __restrict__ WoT,
                                                 const float* __restrict__ bout,
                                                 const int* __restrict__ avgflag,
                                                 float* __restrict__ out, int N) {
    int t = threadIdx.x;
    int r0 = blockIdx.x * 64;
    if (*avgflag) {
        for (int i = t; i < 64 * 128; i += 256) {
            int n = r0 + (i >> 7), j = i & 127;
            if (n < N) {
                float s = 0.f;
#pragma unroll
                for (int h = 0; h < 4; ++h) s += bf2f(agg[(size_t)n * 512 + h * 128 + j]);
                float v = bf2f(T[(size_t)n * 704 + j]) + 0.25f * s;
                out[(size_t)n * 128 + j] = v > 0.f ? v : 0.f;
            }
        }
        return;
    }
    __shared__ u16 Asm[64][72];
    __shared__ u16 Bsm[128][72];
    int lane = t & 63, wave = t >> 6;
    int wm = wave >> 1, wn = wave & 1;
    int lr = lane & 15, lk = lane >> 4;
    f4 acc[2][4] = {};
    for (int kb = 0; kb < 8; ++kb) {
        if (kb) __syncthreads();
        {  // stage A: agg (bf16) rows r0..+64, k = kb*64..
            int row = t >> 2, ks = (t & 3) * 16;
            int r = r0 + row;
            uint4 v0 = {0, 0, 0, 0}, v1 = {0, 0, 0, 0};
            if (r < N) {
                const u16* src = &agg[(size_t)r * 512 + kb * 64 + ks];
                v0 = *(const uint4*)src;
                v1 = *(const uint4*)(src + 8);
            }
            *(uint4*)&Asm[row][ks] = v0;
            *(uint4*)&Asm[row][ks + 8] = v1;
        }
        {  // stage B: WoT [col][k]
            int col = t >> 1, ks = (t & 1) * 32;
            const u16* src = &WoT[(size_t)col * 512 + kb * 64 + ks];
            uint4 v0 = *(const uint4*)src;
            uint4 v1 = *(const uint4*)(src + 8);
            uint4 v2 = *(const uint4*)(src + 16);
            uint4 v3 = *(const uint4*)(src + 24);
            *(uint4*)&Bsm[col][ks] = v0;
            *(uint4*)&Bsm[col][ks + 8] = v1;
            *(uint4*)&Bsm[col][ks + 16] = v2;
            *(uint4*)&Bsm[col][ks + 24] = v3;
        }
        __syncthreads();
#pragma unroll
        for (int kk = 0; kk < 2; ++kk) {
            bh8 a[2], b[4];
#pragma unroll
            for (int am = 0; am < 2; ++am)
                a[am] = *(const bh8*)&Asm[wm * 32 + am * 16 + lr][kk * 32 + lk * 8];
#pragma unroll
            for (int bn = 0; bn < 4; ++bn)
                b[bn] = *(const bh8*)&Bsm[wn * 64 + bn * 16 + lr][kk * 32 + lk * 8];
#pragma unroll
            for (int am = 0; am < 2; ++am)
#pragma unroll
                for (int bn = 0; bn < 4; ++bn)
                    acc[am][bn] = __builtin_amdgcn_mfma_f32_16x16x32_bf16(a[am], b[bn], acc[am][bn], 0, 0, 0);
        }
    }
#pragma unroll
    for (int am = 0; am < 2; ++am)
#pragma unroll
        for (int bn = 0; bn < 4; ++bn) {
            int c = wn * 64 + bn * 16 + lr;
            float bc = bout[c];
#pragma unroll
            for (int q = 0; q < 4; ++q) {
                int r = r0 + wm * 32 + am * 16 + lk * 4 + q;
                if (r < N) {
                    float v = acc[am][bn][q] + bc + bf2f(T[(size_t)r * 704 + c]);
                    out[(size_t)r * 128 + c] = v > 0.f ? v : 0.f;
                }
            }
        }
}

// ---------------- launch --------------------------------------------------------------
extern "C" void kernel_launch(void* const* d_in, const int* in_sizes, int n_in, void* d_out,
                              int out_size, void* d_ws, size_t ws_size, hipStream_t stream) {
    const float* nodes = (const float*)d_in[0];
    const float* edges = (const float*)d_in[1];
    const int* senders = (const int*)d_in[2];
    const int* receivers = (const int*)d_in[3];
    const int* avgflag = (const int*)d_in[4];
    const float* W_node = (const float*)d_in[5];
    const float* b_node = (const float*)d_in[6];
    const float* W_edge = (const float*)d_in[7];
    const float* b_edge = (const float*)d_in[8];
    const float* Wk_s = (const float*)d_in[9];
    const float* bk_s = (const float*)d_in[10];
    const float* Wk_r = (const float*)d_in[11];
    const float* bk_r = (const float*)d_in[12];
    const float* W_out = (const float*)d_in[13];
    const float* b_out = (const float*)d_in[14];
    int N = in_sizes[0] / 64;
    int E = in_sizes[2];
    float* outp = (float*)d_out;

    char* base = (char*)d_ws;
    size_t off = 0;
    auto alloc = [&](size_t nbytes) -> char* {
        char* p = base + off;
        off = (off + nbytes + 255) & ~(size_t)255;
        return p;
    };
    u16* T = (u16*)alloc((size_t)N * 704 * 2);
    float* S = (float*)alloc((size_t)N * 4 * 4);
    u16* agg = (u16*)alloc((size_t)N * 512 * 2);
    int* deg = (int*)alloc((size_t)N * 4);
    int* row_start = (int*)alloc((size_t)(N + 1) * 4);
    int* cursor = (int*)alloc((size_t)N * 4);
    int* eidx = (int*)alloc((size_t)E * 4);
    float* A = (float*)alloc((size_t)4 * 64 * 128 * 4);
    float* B = (float*)alloc((size_t)4 * 64 * 128 * 4);
    float* ybr = (float*)alloc((size_t)4 * 128 * 4);
    float* ybs = (float*)alloc((size_t)4 * 128 * 4);
    float* Wfold = (float*)alloc((size_t)64 * 708 * 4);
    float* biasrow = (float*)alloc((size_t)712 * 4);
    u16* WfT = (u16*)alloc((size_t)768 * 64 * 2);
    u16* WoT = (u16*)alloc((size_t)128 * 512 * 2);

    hipMemsetAsync(deg, 0, (size_t)N * 4, stream);
    k0a_kernel<<<256, 256, 0, stream>>>(W_node, Wk_s, Wk_r, A, B);
    k0a2_kernel<<<4, 256, 0, stream>>>(b_node, Wk_s, Wk_r, bk_s, bk_r, ybs, ybr);
    k0b_kernel<<<(65 * 708 + 255) / 256, 256, 0, stream>>>(W_node, b_node, A, B, ybr, ybs,
                                                           Wk_s, W_edge, bk_s, b_edge, Wfold,
                                                           biasrow);
    wconv_kernel<<<(768 * 64 + 128 * 512 + 255) / 256, 256, 0, stream>>>(Wfold, W_out, WfT, WoT);
    dim3 g1grid((N + 63) / 64, 6);
    g1_kernel<<<g1grid, 256, 0, stream>>>(nodes, WfT, biasrow, T, S, N);
    hist_kernel<<<(E + 255) / 256, 256, 0, stream>>>(receivers, deg, E);
    scan_kernel<<<1, 1024, 0, stream>>>(deg, row_start, cursor, N);
    scatter_kernel<<<(E + 255) / 256, 256, 0, stream>>>(receivers, cursor, eidx, E);
    en_kernel<<<4096, 256, 0, stream>>>(row_start, eidx, senders, edges, T, S, W_edge,
                                        b_edge, agg, N);
    g3_kernel<<<(N + 63) / 64, 256, 0, stream>>>(T, agg, WoT, b_out, avgflag, outp, N);
}